// Round 9
// baseline (205.835 us; speedup 1.0000x reference)
//
#include <hip/hip_runtime.h>

typedef _Float16 f16;
typedef f16 f16x2 __attribute__((ext_vector_type(2)));
typedef f16 f16x8 __attribute__((ext_vector_type(8)));
typedef float f32x4 __attribute__((ext_vector_type(4)));

#define BSH 7                  // 128 nodes per bucket
#define BN 128
#define CHUNK 4096             // edges per count/place block
#define LCAP 4096              // LDS edge cap per bucket (mean ~2046, +45 sigma)
#define NBMAX 512
#define PMAX 512               // padded partial count (nb2 <= 512)

// ============ K1: bucket-hist (blocks 0..nblk) || MFMA GEMM1 (remaining blocks) ============
__global__ __launch_bounds__(256) void k1(const float* __restrict__ x,
                                          const float* __restrict__ W1,
                                          const int* __restrict__ dst, f16* __restrict__ h,
                                          int* __restrict__ histG, int N, int E, int NB,
                                          int nblk) {
    __shared__ int hist[NBMAX];
    __shared__ f16 aT[64 * 136];   // x tile [row][k]
    __shared__ f16 bT[128 * 136];  // W1^T  [n][k]
    const int t = threadIdx.x;

    if ((int)blockIdx.x < nblk) {  // ---- count role ----
        const int blk = blockIdx.x;
        for (int i = t; i < NB; i += 256) hist[i] = 0;
        __syncthreads();
        int lo = blk * CHUNK, hi = min(lo + CHUNK, E);
        for (int i = lo + t; i < hi; i += 256) atomicAdd(&hist[dst[i] >> BSH], 1);
        __syncthreads();
        for (int i = t; i < NB; i += 256) histG[(size_t)i * nblk + blk] = hist[i];
        return;
    }

    // ---- gemm role: h[64 x 128] = x_tile @ W1 ----
    const int gb = blockIdx.x - nblk;
    const int row0 = gb * 64;
    {  // stage A (fp32 -> fp16), k-contiguous
        int r = t >> 2, s = (t & 3) * 32;
        bool ok = (row0 + r) < N;
        const float* xp = x + (size_t)(row0 + r) * 128 + s;
        f16* dp = &aT[r * 136 + s];
#pragma unroll
        for (int c = 0; c < 4; ++c) {
            f16x8 hv;
            if (ok) {
                float4 f0 = *(const float4*)(xp + c * 8);
                float4 f1 = *(const float4*)(xp + c * 8 + 4);
                hv[0] = (f16)f0.x; hv[1] = (f16)f0.y; hv[2] = (f16)f0.z; hv[3] = (f16)f0.w;
                hv[4] = (f16)f1.x; hv[5] = (f16)f1.y; hv[6] = (f16)f1.z; hv[7] = (f16)f1.w;
            } else {
#pragma unroll
                for (int j = 0; j < 8; ++j) hv[j] = (f16)0.f;
            }
            *(f16x8*)(dp + c * 8) = hv;
        }
    }
    for (int idx = t; idx < 128 * 128; idx += 256) {  // stage W1^T
        int k = idx >> 7, n = idx & 127;
        bT[n * 136 + k] = (f16)W1[idx];
    }
    __syncthreads();

    const int w = t >> 6, lane = t & 63, m15 = lane & 15, quad = lane >> 4;
    f32x4 acc[8];
#pragma unroll
    for (int c = 0; c < 8; ++c) acc[c] = (f32x4){0.f, 0.f, 0.f, 0.f};
    const f16* ar = &aT[(w * 16 + m15) * 136 + quad * 8];
#pragma unroll
    for (int k0 = 0; k0 < 128; k0 += 32) {
        f16x8 a = *(const f16x8*)(ar + k0);
#pragma unroll
        for (int c = 0; c < 8; ++c) {
            f16x8 b = *(const f16x8*)(&bT[(c * 16 + m15) * 136 + k0 + quad * 8]);
            acc[c] = __builtin_amdgcn_mfma_f32_16x16x32_f16(a, b, acc[c], 0, 0, 0);
        }
    }
#pragma unroll
    for (int c = 0; c < 8; ++c)
#pragma unroll
        for (int r = 0; r < 4; ++r) {
            int row = row0 + w * 16 + quad * 4 + r;
            if (row < N) h[(size_t)row * 128 + c * 16 + m15] = (f16)acc[c][r];
        }
}

// ============ K2: per-256-chunk exclusive scan (in place), partials to bsum ============
__global__ __launch_bounds__(256) void scanA(int* __restrict__ a, int* __restrict__ bsum, int L) {
    __shared__ int tmp[256];
    int tid = threadIdx.x;
    int i = blockIdx.x * 256 + tid;
    int v = (i < L) ? a[i] : 0;
    tmp[tid] = v;
    __syncthreads();
    for (int o = 1; o < 256; o <<= 1) {
        int t2 = (tid >= o) ? tmp[tid - o] : 0;
        __syncthreads();
        tmp[tid] += t2;
        __syncthreads();
    }
    if (i < L) a[i] = tmp[tid] - v;  // exclusive within chunk
    if (tid == 255) bsum[blockIdx.x] = tmp[255];
}

// ---- device helper: exclusive-scan bsum[nb2] into LDS excl[PMAX] (256-thread block) ----
__device__ __forceinline__ void scan_partials(const int* __restrict__ bsum, int nb2,
                                              int* excl /*PMAX*/, int* work /*PMAX*/) {
    const int t = threadIdx.x & 255;  // works for 256-thread blocks
#pragma unroll
    for (int i = t; i < PMAX; i += 256) work[i] = (i < nb2) ? bsum[i] : 0;
    __syncthreads();
    // Hillis-Steele inclusive over PMAX with ping-pong
    for (int o = 1; o < PMAX; o <<= 1) {
        for (int i = t; i < PMAX; i += 256)
            excl[i] = work[i] + ((i >= o) ? work[i - o] : 0);
        __syncthreads();
        for (int i = t; i < PMAX; i += 256) work[i] = excl[i];
        __syncthreads();
    }
    // exclusive = inclusive shifted
    for (int i = t; i < PMAX; i += 256) excl[i] = (i == 0) ? 0 : work[i - 1];
    __syncthreads();
}

// ============ K3: place edges into bucket-contiguous sorted[] (partial-scan folded) ============
__global__ __launch_bounds__(256) void place(const int* __restrict__ src,
                                             const int* __restrict__ dst,
                                             const int* __restrict__ histG,
                                             const int* __restrict__ bsum, int nb2,
                                             int* __restrict__ sorted, int E, int NB, int nblk) {
    __shared__ int excl[PMAX];
    __shared__ int work[PMAX];
    __shared__ int ofs[NBMAX];
    const int t = threadIdx.x, blk = blockIdx.x;
    scan_partials(bsum, nb2, excl, work);
    for (int i = t; i < NB; i += 256) {
        int idx = i * nblk + blk;
        ofs[i] = histG[idx] + excl[idx >> 8];
    }
    __syncthreads();
    int lo = blk * CHUNK, hi = min(lo + CHUNK, E);
    for (int i = lo + t; i < hi; i += 256) {
        int d = dst[i];
        int pos = atomicAdd(&ofs[d >> BSH], 1);
        sorted[pos] = (src[i] << BSH) | (d & (BN - 1));
    }
}

// ============ K4: per-bucket node-sort -> rowstart, dinv, csr_src ============
__global__ __launch_bounds__(256) void bucket_build(const int* __restrict__ histG,
                                                    const int* __restrict__ bsum, int nb2,
                                                    const int* __restrict__ sorted,
                                                    int* __restrict__ rowstart,
                                                    float* __restrict__ dinv,
                                                    int* __restrict__ csr_src, int N, int E,
                                                    int NB, int nblk) {
    __shared__ int ent[LCAP];
    __shared__ int hist[BN];
    __shared__ int lofs[BN];
    __shared__ int excl[PMAX];
    __shared__ int work[PMAX];
    const int b = blockIdx.x, t = threadIdx.x;
    scan_partials(bsum, nb2, excl, work);

    const int i0 = b * nblk;
    const int base = histG[i0] + excl[i0 >> 8];
    const int endb = (b == NB - 1) ? E : (histG[i0 + nblk] + excl[(i0 + nblk) >> 8]);
    int total = min(endb - base, LCAP);
    if (b == 0 && t == 0) rowstart[N] = E;

    for (int i = t; i < total; i += 256) ent[i] = sorted[base + i];
    if (t < BN) hist[t] = 0;
    __syncthreads();
    for (int i = t; i < total; i += 256) atomicAdd(&hist[ent[i] & (BN - 1)], 1);
    __syncthreads();
    if (t < BN) lofs[t] = hist[t];
    __syncthreads();
    for (int o = 1; o < BN; o <<= 1) {
        int v = (t < BN && t >= o) ? lofs[t - o] : 0;
        __syncthreads();
        if (t < BN) lofs[t] += v;
        __syncthreads();
    }
    if (t < BN) {
        int ex = lofs[t] - hist[t];
        int node = (b << BSH) + t;
        if (node < N) {
            rowstart[node] = base + ex;
            dinv[node] = rsqrtf((float)hist[t] + 1.0f);  // +1 self-loop
        }
        lofs[t] = ex;
    }
    __syncthreads();
    for (int i = t; i < total; i += 256) {
        int e = ent[i];
        int pos = atomicAdd(&lofs[e & (BN - 1)], 1);
        csr_src[base + pos] = e >> BSH;
    }
}

// ============ K5: gather1 + bias + relu (1 wave/node) fused with MFMA GEMM2 ============
// 1024 threads = 16 waves = 16 nodes/block; r1 tile stays in LDS; waves 0-3 do the GEMM.
__global__ __launch_bounds__(1024) void g1_gemm2(const int* __restrict__ rowstart,
                                                 const int* __restrict__ csr_src,
                                                 const float* __restrict__ dinv,
                                                 const f16* __restrict__ h,
                                                 const float* __restrict__ b1,
                                                 const float* __restrict__ W2,
                                                 f16* __restrict__ h2, int N) {
    __shared__ f16 r1s[16 * 136];  // r1 tile [node][feat]
    __shared__ f16 bT[64 * 136];   // W2^T [n][k]
    const int t = threadIdx.x, w = t >> 6, lane = t & 63;

    for (int idx = t; idx < 128 * 64; idx += 1024) {  // stage W2^T
        int k = idx >> 6, n = idx & 63;
        bT[n * 136 + k] = (f16)W2[idx];
    }

    const int node = blockIdx.x * 16 + w;
    if (node < N) {
        int beg = rowstart[node], end = rowstart[node + 1];
        float dn = dinv[node];
        const f16x2* hv = (const f16x2*)h;

        f16x2 sv = hv[(size_t)node * 64 + lane];
        float ax = dn * (float)sv[0], ay = dn * (float)sv[1];
        int i = beg;
        for (; i + 4 <= end; i += 4) {
            int s0 = csr_src[i], s1 = csr_src[i + 1], s2 = csr_src[i + 2], s3 = csr_src[i + 3];
            float w0 = dinv[s0], w1 = dinv[s1], w2 = dinv[s2], w3 = dinv[s3];
            f16x2 v0 = hv[(size_t)s0 * 64 + lane];
            f16x2 v1 = hv[(size_t)s1 * 64 + lane];
            f16x2 v2 = hv[(size_t)s2 * 64 + lane];
            f16x2 v3 = hv[(size_t)s3 * 64 + lane];
            ax = fmaf(w0, (float)v0[0], ax); ay = fmaf(w0, (float)v0[1], ay);
            ax = fmaf(w1, (float)v1[0], ax); ay = fmaf(w1, (float)v1[1], ay);
            ax = fmaf(w2, (float)v2[0], ax); ay = fmaf(w2, (float)v2[1], ay);
            ax = fmaf(w3, (float)v3[0], ax); ay = fmaf(w3, (float)v3[1], ay);
        }
        for (; i < end; ++i) {
            int s = csr_src[i];
            float ws = dinv[s];
            f16x2 v = hv[(size_t)s * 64 + lane];
            ax = fmaf(ws, (float)v[0], ax);
            ay = fmaf(ws, (float)v[1], ay);
        }
        float2 bb = ((const float2*)b1)[lane];
        float ox = fmaxf(fmaf(dn, ax, bb.x), 0.f);
        float oy = fmaxf(fmaf(dn, ay, bb.y), 0.f);
        *(f16x2*)(&r1s[w * 136 + 2 * lane]) = (f16x2){(f16)ox, (f16)oy};
    } else {
        *(f16x2*)(&r1s[w * 136 + 2 * lane]) = (f16x2){(f16)0.f, (f16)0.f};
    }
    __syncthreads();

    // ---- GEMM2 tile: h2[16 x 64] = r1s @ W2 ; wave c (0..3) does n-block c ----
    if (w < 4) {
        const int m15 = lane & 15, quad = lane >> 4;
        f32x4 acc = (f32x4){0.f, 0.f, 0.f, 0.f};
        const f16* ar = &r1s[m15 * 136 + quad * 8];
#pragma unroll
        for (int k0 = 0; k0 < 128; k0 += 32) {
            f16x8 a = *(const f16x8*)(ar + k0);
            f16x8 b = *(const f16x8*)(&bT[(w * 16 + m15) * 136 + k0 + quad * 8]);
            acc = __builtin_amdgcn_mfma_f32_16x16x32_f16(a, b, acc, 0, 0, 0);
        }
#pragma unroll
        for (int r = 0; r < 4; ++r) {
            int row = blockIdx.x * 16 + quad * 4 + r;
            if (row < N) h2[(size_t)row * 64 + w * 16 + m15] = (f16)acc[r];
        }
    }
}

// ============ K6: gather2 + bias -> fp32 out (1 wave / node) ============
__global__ __launch_bounds__(256) void gather2(const int* __restrict__ rowstart,
                                               const int* __restrict__ csr_src,
                                               const float* __restrict__ dinv,
                                               const f16* __restrict__ h2,
                                               const float* __restrict__ b2,
                                               float* __restrict__ out, int N) {
    int node = (blockIdx.x * 256 + threadIdx.x) >> 6;
    int lane = threadIdx.x & 63;
    if (node >= N) return;
    int beg = rowstart[node], end = rowstart[node + 1];
    float dn = dinv[node];

    float a = dn * (float)h2[(size_t)node * 64 + lane];
    int i = beg;
    for (; i + 4 <= end; i += 4) {
        int s0 = csr_src[i], s1 = csr_src[i + 1], s2 = csr_src[i + 2], s3 = csr_src[i + 3];
        float w0 = dinv[s0], w1 = dinv[s1], w2 = dinv[s2], w3 = dinv[s3];
        float v0 = (float)h2[(size_t)s0 * 64 + lane];
        float v1 = (float)h2[(size_t)s1 * 64 + lane];
        float v2 = (float)h2[(size_t)s2 * 64 + lane];
        float v3 = (float)h2[(size_t)s3 * 64 + lane];
        a = fmaf(w0, v0, a);
        a = fmaf(w1, v1, a);
        a = fmaf(w2, v2, a);
        a = fmaf(w3, v3, a);
    }
    for (; i < end; ++i) {
        int s = csr_src[i];
        a = fmaf(dinv[s], (float)h2[(size_t)s * 64 + lane], a);
    }
    out[(size_t)node * 64 + lane] = fmaf(dn, a, b2[lane]);
}

extern "C" void kernel_launch(void* const* d_in, const int* in_sizes, int n_in,
                              void* d_out, int out_size, void* d_ws, size_t ws_size,
                              hipStream_t stream) {
    const float* x  = (const float*)d_in[0];
    const int*   ei = (const int*)d_in[1];
    const float* W1 = (const float*)d_in[2];
    const float* b1 = (const float*)d_in[3];
    const float* W2 = (const float*)d_in[4];
    const float* b2 = (const float*)d_in[5];

    const int N = in_sizes[0] / 128;  // 50000
    const int E = in_sizes[1] / 2;    // 800000
    const int* src = ei;
    const int* dst = ei + E;
    const int NB   = (N + BN - 1) >> BSH;      // 391
    const int nblk = (E + CHUNK - 1) / CHUNK;  // 196
    const int L    = NB * nblk;                // 76,636
    const int nb2  = (L + 255) / 256;          // 300 <= PMAX

    char* p = (char*)d_ws;
    auto bump = [&](size_t bytes) {
        char* r = p;
        p += (bytes + 255) & ~(size_t)255;
        return r;
    };
    int*   histG    = (int*)bump((size_t)L * 4);
    int*   bsum     = (int*)bump((size_t)nb2 * 4);
    int*   sorted   = (int*)bump((size_t)E * 4);
    int*   rowstart = (int*)bump((size_t)(N + 1) * 4);
    float* dinv     = (float*)bump((size_t)N * 4);
    int*   csr_src  = (int*)bump((size_t)E * 4);
    f16*   h        = (f16*)bump((size_t)N * 128 * 2);
    f16*   h2       = (f16*)bump((size_t)N * 64 * 2);
    float* out      = (float*)d_out;

    // K1: bucket-hist || MFMA gemm1 (x@W1 -> h f16)
    k1<<<nblk + (N + 63) / 64, 256, 0, stream>>>(x, W1, dst, h, histG, N, E, NB, nblk);
    // K2: chunk-local scan of histG + partials
    scanA<<<nb2, 256, 0, stream>>>(histG, bsum, L);
    // K3: place edges bucket-contiguously (partial-scan in prologue)
    place<<<nblk, 256, 0, stream>>>(src, dst, histG, bsum, nb2, sorted, E, NB, nblk);
    // K4: per-bucket node sort -> rowstart, dinv, csr_src
    bucket_build<<<NB, 256, 0, stream>>>(histG, bsum, nb2, sorted, rowstart, dinv, csr_src, N, E,
                                         NB, nblk);
    // K5: gather1 + b1 + relu + gemm2 -> h2 (f16), r1 never leaves LDS
    g1_gemm2<<<(N + 15) / 16, 1024, 0, stream>>>(rowstart, csr_src, dinv, h, b1, W2, h2, N);
    // K6: gather2 + b2 -> out (fp32)
    gather2<<<(N + 3) / 4, 256, 0, stream>>>(rowstart, csr_src, dinv, h2, b2, out, N);
}

// Round 11
// 194.395 us; speedup vs baseline: 1.0588x; 1.0588x over previous
//
#include <hip/hip_runtime.h>

typedef _Float16 f16;
typedef f16 f16x2 __attribute__((ext_vector_type(2)));
typedef f16 f16x8 __attribute__((ext_vector_type(8)));
typedef float f32x4 __attribute__((ext_vector_type(4)));

#define BSH 7                  // 128 nodes per bucket
#define BN 128
#define CHUNK 4096             // edges per count/place block
#define LCAP 4096              // LDS edge cap per bucket (mean ~2046, +45 sigma)
#define NBMAX 512
#define PMAX 512               // padded partial count (nb2 <= 512)

// ============ K1: bucket-hist (blocks 0..nblk) || MFMA GEMM1 (remaining blocks) ============
__global__ __launch_bounds__(256) void k1(const float* __restrict__ x,
                                          const float* __restrict__ W1,
                                          const int* __restrict__ dst, f16* __restrict__ h,
                                          int* __restrict__ histG, int N, int E, int NB,
                                          int nblk) {
    __shared__ int hist[NBMAX];
    __shared__ f16 aT[64 * 136];   // x tile [row][k]
    __shared__ f16 bT[128 * 136];  // W1^T  [n][k]
    const int t = threadIdx.x;

    if ((int)blockIdx.x < nblk) {  // ---- count role ----
        const int blk = blockIdx.x;
        for (int i = t; i < NB; i += 256) hist[i] = 0;
        __syncthreads();
        int lo = blk * CHUNK, hi = min(lo + CHUNK, E);
        for (int i = lo + t; i < hi; i += 256) atomicAdd(&hist[dst[i] >> BSH], 1);
        __syncthreads();
        for (int i = t; i < NB; i += 256) histG[(size_t)i * nblk + blk] = hist[i];
        return;
    }

    // ---- gemm role: h[64 x 128] = x_tile @ W1 ----
    const int gb = blockIdx.x - nblk;
    const int row0 = gb * 64;
    {  // stage A (fp32 -> fp16), k-contiguous
        int r = t >> 2, s = (t & 3) * 32;
        bool ok = (row0 + r) < N;
        const float* xp = x + (size_t)(row0 + r) * 128 + s;
        f16* dp = &aT[r * 136 + s];
#pragma unroll
        for (int c = 0; c < 4; ++c) {
            f16x8 hv;
            if (ok) {
                float4 f0 = *(const float4*)(xp + c * 8);
                float4 f1 = *(const float4*)(xp + c * 8 + 4);
                hv[0] = (f16)f0.x; hv[1] = (f16)f0.y; hv[2] = (f16)f0.z; hv[3] = (f16)f0.w;
                hv[4] = (f16)f1.x; hv[5] = (f16)f1.y; hv[6] = (f16)f1.z; hv[7] = (f16)f1.w;
            } else {
#pragma unroll
                for (int j = 0; j < 8; ++j) hv[j] = (f16)0.f;
            }
            *(f16x8*)(dp + c * 8) = hv;
        }
    }
    for (int idx = t; idx < 128 * 128; idx += 256) {  // stage W1^T
        int k = idx >> 7, n = idx & 127;
        bT[n * 136 + k] = (f16)W1[idx];
    }
    __syncthreads();

    const int w = t >> 6, lane = t & 63, m15 = lane & 15, quad = lane >> 4;
    f32x4 acc[8];
#pragma unroll
    for (int c = 0; c < 8; ++c) acc[c] = (f32x4){0.f, 0.f, 0.f, 0.f};
    const f16* ar = &aT[(w * 16 + m15) * 136 + quad * 8];
#pragma unroll
    for (int k0 = 0; k0 < 128; k0 += 32) {
        f16x8 a = *(const f16x8*)(ar + k0);
#pragma unroll
        for (int c = 0; c < 8; ++c) {
            f16x8 b = *(const f16x8*)(&bT[(c * 16 + m15) * 136 + k0 + quad * 8]);
            acc[c] = __builtin_amdgcn_mfma_f32_16x16x32_f16(a, b, acc[c], 0, 0, 0);
        }
    }
#pragma unroll
    for (int c = 0; c < 8; ++c)
#pragma unroll
        for (int r = 0; r < 4; ++r) {
            int row = row0 + w * 16 + quad * 4 + r;
            if (row < N) h[(size_t)row * 128 + c * 16 + m15] = (f16)acc[c][r];
        }
}

// ============ K2: per-256-chunk exclusive scan (in place), partials to bsum ============
__global__ __launch_bounds__(256) void scanA(int* __restrict__ a, int* __restrict__ bsum, int L) {
    __shared__ int tmp[256];
    int tid = threadIdx.x;
    int i = blockIdx.x * 256 + tid;
    int v = (i < L) ? a[i] : 0;
    tmp[tid] = v;
    __syncthreads();
    for (int o = 1; o < 256; o <<= 1) {
        int t2 = (tid >= o) ? tmp[tid - o] : 0;
        __syncthreads();
        tmp[tid] += t2;
        __syncthreads();
    }
    if (i < L) a[i] = tmp[tid] - v;  // exclusive within chunk
    if (tid == 255) bsum[blockIdx.x] = tmp[255];
}

// ---- device helper: exclusive-scan bsum[nb2] into LDS excl[PMAX] (256-thread block) ----
__device__ __forceinline__ void scan_partials(const int* __restrict__ bsum, int nb2,
                                              int* excl /*PMAX*/, int* work /*PMAX*/) {
    const int t = threadIdx.x & 255;
    for (int i = t; i < PMAX; i += 256) work[i] = (i < nb2) ? bsum[i] : 0;
    __syncthreads();
    for (int o = 1; o < PMAX; o <<= 1) {
        for (int i = t; i < PMAX; i += 256) excl[i] = work[i] + ((i >= o) ? work[i - o] : 0);
        __syncthreads();
        for (int i = t; i < PMAX; i += 256) work[i] = excl[i];
        __syncthreads();
    }
    for (int i = t; i < PMAX; i += 256) excl[i] = (i == 0) ? 0 : work[i - 1];
    __syncthreads();
}

// ============ K3: place edges into bucket-contiguous sorted[] (partial-scan folded) ============
__global__ __launch_bounds__(256) void place(const int* __restrict__ src,
                                             const int* __restrict__ dst,
                                             const int* __restrict__ histG,
                                             const int* __restrict__ bsum, int nb2,
                                             int* __restrict__ sorted, int E, int NB, int nblk) {
    __shared__ int excl[PMAX];
    __shared__ int work[PMAX];
    __shared__ int ofs[NBMAX];
    const int t = threadIdx.x, blk = blockIdx.x;
    scan_partials(bsum, nb2, excl, work);
    for (int i = t; i < NB; i += 256) {
        int idx = i * nblk + blk;
        ofs[i] = histG[idx] + excl[idx >> 8];
    }
    __syncthreads();
    int lo = blk * CHUNK, hi = min(lo + CHUNK, E);
    for (int i = lo + t; i < hi; i += 256) {
        int d = dst[i];
        int pos = atomicAdd(&ofs[d >> BSH], 1);
        sorted[pos] = (src[i] << BSH) | (d & (BN - 1));
    }
}

// ============ K4: per-bucket node-sort -> rowstart, dinv, csr_src ============
__global__ __launch_bounds__(256) void bucket_build(const int* __restrict__ histG,
                                                    const int* __restrict__ bsum, int nb2,
                                                    const int* __restrict__ sorted,
                                                    int* __restrict__ rowstart,
                                                    float* __restrict__ dinv,
                                                    int* __restrict__ csr_src, int N, int E,
                                                    int NB, int nblk) {
    __shared__ int ent[LCAP];
    __shared__ int hist[BN];
    __shared__ int lofs[BN];
    __shared__ int excl[PMAX];
    __shared__ int work[PMAX];
    const int b = blockIdx.x, t = threadIdx.x;
    scan_partials(bsum, nb2, excl, work);

    const int i0 = b * nblk;
    const int base = histG[i0] + excl[i0 >> 8];
    const int endb = (b == NB - 1) ? E : (histG[i0 + nblk] + excl[(i0 + nblk) >> 8]);
    int total = min(endb - base, LCAP);
    if (b == 0 && t == 0) rowstart[N] = E;

    for (int i = t; i < total; i += 256) ent[i] = sorted[base + i];
    if (t < BN) hist[t] = 0;
    __syncthreads();
    for (int i = t; i < total; i += 256) atomicAdd(&hist[ent[i] & (BN - 1)], 1);
    __syncthreads();
    if (t < BN) lofs[t] = hist[t];
    __syncthreads();
    for (int o = 1; o < BN; o <<= 1) {
        int v = (t < BN && t >= o) ? lofs[t - o] : 0;
        __syncthreads();
        if (t < BN) lofs[t] += v;
        __syncthreads();
    }
    if (t < BN) {
        int ex = lofs[t] - hist[t];
        int node = (b << BSH) + t;
        if (node < N) {
            rowstart[node] = base + ex;
            dinv[node] = rsqrtf((float)hist[t] + 1.0f);  // +1 self-loop
        }
        lofs[t] = ex;
    }
    __syncthreads();
    for (int i = t; i < total; i += 256) {
        int e = ent[i];
        int pos = atomicAdd(&lofs[e & (BN - 1)], 1);
        csr_src[base + pos] = e >> BSH;
    }
}

// ============ K5: gather1 + bias + relu (1 wave / node), f16 ============
__global__ __launch_bounds__(256) void gather1(const int* __restrict__ rowstart,
                                               const int* __restrict__ csr_src,
                                               const float* __restrict__ dinv,
                                               const f16* __restrict__ h,
                                               const float* __restrict__ b1,
                                               f16* __restrict__ r1, int N) {
    int node = (blockIdx.x * 256 + threadIdx.x) >> 6;
    int lane = threadIdx.x & 63;
    if (node >= N) return;
    int beg = rowstart[node], end = rowstart[node + 1];
    float dn = dinv[node];
    const f16x2* hv = (const f16x2*)h;

    f16x2 sv = hv[(size_t)node * 64 + lane];
    float ax = dn * (float)sv[0], ay = dn * (float)sv[1];
    int i = beg;
    for (; i + 4 <= end; i += 4) {
        int s0 = csr_src[i], s1 = csr_src[i + 1], s2 = csr_src[i + 2], s3 = csr_src[i + 3];
        float w0 = dinv[s0], w1 = dinv[s1], w2 = dinv[s2], w3 = dinv[s3];
        f16x2 v0 = hv[(size_t)s0 * 64 + lane];
        f16x2 v1 = hv[(size_t)s1 * 64 + lane];
        f16x2 v2 = hv[(size_t)s2 * 64 + lane];
        f16x2 v3 = hv[(size_t)s3 * 64 + lane];
        ax = fmaf(w0, (float)v0[0], ax); ay = fmaf(w0, (float)v0[1], ay);
        ax = fmaf(w1, (float)v1[0], ax); ay = fmaf(w1, (float)v1[1], ay);
        ax = fmaf(w2, (float)v2[0], ax); ay = fmaf(w2, (float)v2[1], ay);
        ax = fmaf(w3, (float)v3[0], ax); ay = fmaf(w3, (float)v3[1], ay);
    }
    for (; i < end; ++i) {
        int s = csr_src[i];
        float w = dinv[s];
        f16x2 v = hv[(size_t)s * 64 + lane];
        ax = fmaf(w, (float)v[0], ax);
        ay = fmaf(w, (float)v[1], ay);
    }
    float2 bb = ((const float2*)b1)[lane];
    float ox = fmaxf(fmaf(dn, ax, bb.x), 0.f);
    float oy = fmaxf(fmaf(dn, ay, bb.y), 0.f);
    ((f16x2*)r1)[(size_t)node * 64 + lane] = (f16x2){(f16)ox, (f16)oy};
}

// ============ K6: MFMA GEMM2: h2[N x 64] = r1 @ W2 ============
__global__ __launch_bounds__(256) void gemm2(const f16* __restrict__ r1,
                                             const float* __restrict__ W2, f16* __restrict__ h2,
                                             int N) {
    __shared__ f16 aT[64 * 136];
    __shared__ f16 bT[64 * 136];  // W2^T [n][k]
    const int t = threadIdx.x;
    const int row0 = blockIdx.x * 64;
    {
        int r = t >> 2, s = (t & 3) * 32;
        bool ok = (row0 + r) < N;
        const f16* rp = r1 + (size_t)(row0 + r) * 128 + s;
        f16* dp = &aT[r * 136 + s];
#pragma unroll
        for (int c = 0; c < 4; ++c) {
            f16x8 hv;
            if (ok) hv = *(const f16x8*)(rp + c * 8);
            else {
#pragma unroll
                for (int j = 0; j < 8; ++j) hv[j] = (f16)0.f;
            }
            *(f16x8*)(dp + c * 8) = hv;
        }
    }
    for (int idx = t; idx < 128 * 64; idx += 256) {  // stage W2^T
        int k = idx >> 6, n = idx & 63;
        bT[n * 136 + k] = (f16)W2[idx];
    }
    __syncthreads();

    const int w = t >> 6, lane = t & 63, m15 = lane & 15, quad = lane >> 4;
    f32x4 acc[4];
#pragma unroll
    for (int c = 0; c < 4; ++c) acc[c] = (f32x4){0.f, 0.f, 0.f, 0.f};
    const f16* ar = &aT[(w * 16 + m15) * 136 + quad * 8];
#pragma unroll
    for (int k0 = 0; k0 < 128; k0 += 32) {
        f16x8 a = *(const f16x8*)(ar + k0);
#pragma unroll
        for (int c = 0; c < 4; ++c) {
            f16x8 b = *(const f16x8*)(&bT[(c * 16 + m15) * 136 + k0 + quad * 8]);
            acc[c] = __builtin_amdgcn_mfma_f32_16x16x32_f16(a, b, acc[c], 0, 0, 0);
        }
    }
#pragma unroll
    for (int c = 0; c < 4; ++c)
#pragma unroll
        for (int r = 0; r < 4; ++r) {
            int row = row0 + w * 16 + quad * 4 + r;
            if (row < N) h2[(size_t)row * 64 + c * 16 + m15] = (f16)acc[c][r];
        }
}

// ============ K7: gather2 + bias -> fp32 out (2 nodes / wave, 32 lanes each) ============
__global__ __launch_bounds__(256) void gather2(const int* __restrict__ rowstart,
                                               const int* __restrict__ csr_src,
                                               const float* __restrict__ dinv,
                                               const f16* __restrict__ h2,
                                               const float* __restrict__ b2,
                                               float* __restrict__ out, int N) {
    int pair = (blockIdx.x * 256 + threadIdx.x) >> 6;  // wave id
    int lane = threadIdx.x & 63;
    int sub = lane >> 5, l32 = lane & 31;
    int node = pair * 2 + sub;
    if (node >= N) return;
    int beg = rowstart[node], end = rowstart[node + 1];
    float dn = dinv[node];
    const f16x2* h2v = (const f16x2*)h2;  // 32 f16x2 per 64-feat row

    f16x2 sv = h2v[(size_t)node * 32 + l32];
    float ax = dn * (float)sv[0], ay = dn * (float)sv[1];
    int i = beg;
    for (; i + 4 <= end; i += 4) {
        int s0 = csr_src[i], s1 = csr_src[i + 1], s2 = csr_src[i + 2], s3 = csr_src[i + 3];
        float w0 = dinv[s0], w1 = dinv[s1], w2 = dinv[s2], w3 = dinv[s3];
        f16x2 v0 = h2v[(size_t)s0 * 32 + l32];
        f16x2 v1 = h2v[(size_t)s1 * 32 + l32];
        f16x2 v2 = h2v[(size_t)s2 * 32 + l32];
        f16x2 v3 = h2v[(size_t)s3 * 32 + l32];
        ax = fmaf(w0, (float)v0[0], ax); ay = fmaf(w0, (float)v0[1], ay);
        ax = fmaf(w1, (float)v1[0], ax); ay = fmaf(w1, (float)v1[1], ay);
        ax = fmaf(w2, (float)v2[0], ax); ay = fmaf(w2, (float)v2[1], ay);
        ax = fmaf(w3, (float)v3[0], ax); ay = fmaf(w3, (float)v3[1], ay);
    }
    for (; i < end; ++i) {
        int s = csr_src[i];
        float w = dinv[s];
        f16x2 v = h2v[(size_t)s * 32 + l32];
        ax = fmaf(w, (float)v[0], ax);
        ay = fmaf(w, (float)v[1], ay);
    }
    float2 bb = ((const float2*)b2)[l32];
    float2 o;
    o.x = fmaf(dn, ax, bb.x);
    o.y = fmaf(dn, ay, bb.y);
    ((float2*)out)[(size_t)node * 32 + l32] = o;
}

extern "C" void kernel_launch(void* const* d_in, const int* in_sizes, int n_in,
                              void* d_out, int out_size, void* d_ws, size_t ws_size,
                              hipStream_t stream) {
    const float* x  = (const float*)d_in[0];
    const int*   ei = (const int*)d_in[1];
    const float* W1 = (const float*)d_in[2];
    const float* b1 = (const float*)d_in[3];
    const float* W2 = (const float*)d_in[4];
    const float* b2 = (const float*)d_in[5];

    const int N = in_sizes[0] / 128;  // 50000
    const int E = in_sizes[1] / 2;    // 800000
    const int* src = ei;
    const int* dst = ei + E;
    const int NB   = (N + BN - 1) >> BSH;      // 391
    const int nblk = (E + CHUNK - 1) / CHUNK;  // 196
    const int L    = NB * nblk;                // 76,636
    const int nb2  = (L + 255) / 256;          // 300 <= PMAX

    char* p = (char*)d_ws;
    auto bump = [&](size_t bytes) {
        char* r = p;
        p += (bytes + 255) & ~(size_t)255;
        return r;
    };
    int*   histG    = (int*)bump((size_t)L * 4);
    int*   bsum     = (int*)bump((size_t)nb2 * 4);
    int*   sorted   = (int*)bump((size_t)E * 4);
    int*   rowstart = (int*)bump((size_t)(N + 1) * 4);
    float* dinv     = (float*)bump((size_t)N * 4);
    int*   csr_src  = (int*)bump((size_t)E * 4);
    f16*   h        = (f16*)bump((size_t)N * 128 * 2);
    f16*   r1       = (f16*)bump((size_t)N * 128 * 2);
    f16*   h2       = (f16*)bump((size_t)N * 64 * 2);
    float* out      = (float*)d_out;

    // K1: bucket-hist || MFMA gemm1 (x@W1 -> h f16)
    k1<<<nblk + (N + 63) / 64, 256, 0, stream>>>(x, W1, dst, h, histG, N, E, NB, nblk);
    // K2: chunk-local scan of histG + partials
    scanA<<<nb2, 256, 0, stream>>>(histG, bsum, L);
    // K3: place edges bucket-contiguously (partial-scan prologue)
    place<<<nblk, 256, 0, stream>>>(src, dst, histG, bsum, nb2, sorted, E, NB, nblk);
    // K4: per-bucket node sort -> rowstart, dinv, csr_src
    bucket_build<<<NB, 256, 0, stream>>>(histG, bsum, nb2, sorted, rowstart, dinv, csr_src, N, E,
                                         NB, nblk);
    // K5: gather1 + b1 + relu -> r1 (f16)
    gather1<<<(N + 3) / 4, 256, 0, stream>>>(rowstart, csr_src, dinv, h, b1, r1, N);
    // K6: MFMA gemm2 (r1@W2 -> h2 f16)
    gemm2<<<(N + 63) / 64, 256, 0, stream>>>(r1, W2, h2, N);
    // K7: gather2 + b2 -> out (fp32), 2 nodes/wave
    gather2<<<(N / 2 + 3) / 4, 256, 0, stream>>>(rowstart, csr_src, dinv, h2, b2, out, N);
}